// Round 3
// baseline (1023.804 us; speedup 1.0000x reference)
//
#include <hip/hip_runtime.h>

typedef __bf16 bf16;
typedef __bf16 bf16x8 __attribute__((ext_vector_type(8)));
typedef float f32x4 __attribute__((ext_vector_type(4)));

#define SCALE_Q 0.17677669529663687f

// ======================= weight prep (transpose+cast, wout hi/lo) =======================
__global__ __launch_bounds__(256) void k_prep_w(const float* __restrict__ wqkv,
                                                const float* __restrict__ wout,
                                                bf16* __restrict__ wqkv_t,
                                                bf16* __restrict__ wout_h,
                                                bf16* __restrict__ wout_l) {
    int n = blockIdx.x, k = threadIdx.x;
    if (n < 768) {
        wqkv_t[n * 256 + k] = (bf16)wqkv[k * 768 + n];
    } else {
        float f = wout[k * 256 + (n - 768)];
        bf16 hi = (bf16)f;
        wout_h[(n - 768) * 256 + k] = hi;
        wout_l[(n - 768) * 256 + k] = (bf16)(f - (float)hi);
    }
}

// ======================= kt build (permute conv_w) =======================
__global__ __launch_bounds__(256) void k_build_kt(const float* __restrict__ conv_w,
                                                  bf16* __restrict__ kt) {
    __shared__ float lds[2304];
    int w = blockIdx.x >> 8, co = blockIdx.x & 255;
    const float* src = conv_w + (size_t)(w * 256 + co) * 2304;
    for (int i = threadIdx.x; i < 2304; i += 256) lds[i] = src[i];
    __syncthreads();
    int b = co >> 4, c0 = (co & 15) << 4;
    size_t rbase = (size_t)(b * 16 + w) * 144;
    for (int i = threadIdx.x; i < 2304; i += 256) {
        int t = i >> 4, m = i & 15;
        kt[(rbase + t) * 256 + c0 + m] = (bf16)lds[m * 144 + t];
    }
}

// ======================= shared MFMA GEMM pieces =======================
__device__ __forceinline__ void stage_tile(const bf16* __restrict__ gsrc, int ld,
                                           bf16* lds_tile) {
    int t = threadIdx.x;
#pragma unroll
    for (int c = 0; c < 2; c++) {
        int i = c * 256 + t;          // 0..511
        int row = i >> 2, part = i & 3;
        uint4 v = *(const uint4*)(gsrc + (size_t)row * ld + (part << 3));
        *(uint4*)(lds_tile + row * 32 + ((part ^ (row & 3)) << 3)) = v;
    }
}

__device__ __forceinline__ void mfma_tile_compute(const bf16* As, const bf16* Bs,
                                                  f32x4 acc[4][4]) {
    int lane = threadIdx.x & 63;
    int wave = threadIdx.x >> 6;
    int wm = (wave >> 1) * 64, wn = (wave & 1) * 64;
    int lrow = lane & 15, quad = lane >> 4;
    bf16x8 af[4], bfr[4];
#pragma unroll
    for (int i = 0; i < 4; i++) {
        int r = wm + i * 16 + lrow;
        af[i] = *(const bf16x8*)(As + r * 32 + ((quad ^ (r & 3)) << 3));
        int n = wn + i * 16 + lrow;
        bfr[i] = *(const bf16x8*)(Bs + n * 32 + ((quad ^ (n & 3)) << 3));
    }
#pragma unroll
    for (int i = 0; i < 4; i++)
#pragma unroll
        for (int j = 0; j < 4; j++)
            acc[i][j] = __builtin_amdgcn_mfma_f32_16x16x32_bf16(af[i], bfr[j], acc[i][j], 0, 0, 0);
}

// ======================= qkv GEMM: out = A(MxK) * Bt(NxK)^T + bias (bf16 out, q scaled) =======================
__global__ __launch_bounds__(256) void k_gemm_qkv(const bf16* __restrict__ A,
                                                  const bf16* __restrict__ Bt,
                                                  const float* __restrict__ bias,
                                                  bf16* __restrict__ outb,
                                                  int N, int K) {
    __shared__ bf16 As[128 * 32];
    __shared__ bf16 Bs[128 * 32];
    int m0 = blockIdx.y * 128, n0 = blockIdx.x * 128;
    f32x4 acc[4][4] = {};
    for (int k0 = 0; k0 < K; k0 += 32) {
        stage_tile(A + (size_t)m0 * K + k0, K, As);
        stage_tile(Bt + (size_t)n0 * K + k0, K, Bs);
        __syncthreads();
        mfma_tile_compute(As, Bs, acc);
        __syncthreads();
    }
    int lane = threadIdx.x & 63, wave = threadIdx.x >> 6;
    int wm = (wave >> 1) * 64, wn = (wave & 1) * 64;
    int lrow = lane & 15, quad = lane >> 4;
#pragma unroll
    for (int i = 0; i < 4; i++)
#pragma unroll
        for (int j = 0; j < 4; j++) {
            int col = n0 + wn + j * 16 + lrow;
            float bv = bias[col];
#pragma unroll
            for (int rr = 0; rr < 4; rr++) {
                int row = m0 + wm + i * 16 + quad * 4 + rr;
                float v = acc[i][j][rr] + bv;
                if (col < 256) v *= SCALE_Q;
                outb[(size_t)row * N + col] = (bf16)v;
            }
        }
}

// ======================= out-proj GEMM, hi/lo A and B, 3 products, f32 out =======================
__global__ __launch_bounds__(256) void k_gemm_split3(const bf16* __restrict__ Ahg,
                                                     const bf16* __restrict__ Alg,
                                                     const bf16* __restrict__ Bhg,
                                                     const bf16* __restrict__ Blg,
                                                     const float* __restrict__ bias,
                                                     float* __restrict__ outf,
                                                     int N, int K) {
    __shared__ bf16 Ah[128 * 32];
    __shared__ bf16 Al[128 * 32];
    __shared__ bf16 Bh[128 * 32];
    __shared__ bf16 Bl[128 * 32];
    int m0 = blockIdx.y * 128, n0 = blockIdx.x * 128;
    f32x4 acc[4][4] = {};
    for (int k0 = 0; k0 < K; k0 += 32) {
        stage_tile(Ahg + (size_t)m0 * K + k0, K, Ah);
        stage_tile(Alg + (size_t)m0 * K + k0, K, Al);
        stage_tile(Bhg + (size_t)n0 * K + k0, K, Bh);
        stage_tile(Blg + (size_t)n0 * K + k0, K, Bl);
        __syncthreads();
        mfma_tile_compute(Ah, Bh, acc);
        mfma_tile_compute(Ah, Bl, acc);
        mfma_tile_compute(Al, Bh, acc);
        __syncthreads();
    }
    int lane = threadIdx.x & 63, wave = threadIdx.x >> 6;
    int wm = (wave >> 1) * 64, wn = (wave & 1) * 64;
    int lrow = lane & 15, quad = lane >> 4;
#pragma unroll
    for (int i = 0; i < 4; i++)
#pragma unroll
        for (int j = 0; j < 4; j++) {
            int col = n0 + wn + j * 16 + lrow;
            float bv = bias[col];
#pragma unroll
            for (int rr = 0; rr < 4; rr++) {
                int row = m0 + wm + i * 16 + quad * 4 + rr;
                outf[(size_t)row * N + col] = acc[i][j][rr] + bv;
            }
        }
}

// ======================= attention (fp32 VALU, per (d,h) block), hi/lo output =======================
__global__ __launch_bounds__(256) void k_attn(const bf16* __restrict__ qkv,
                                              bf16* __restrict__ oh,
                                              bf16* __restrict__ ol) {
    __shared__ unsigned short kS[144 * 32];
    __shared__ unsigned short vS[144 * 32];
    __shared__ float sS[144 * 144];
    int d = blockIdx.x >> 3, h = blockIdx.x & 7;
    const unsigned short* base = (const unsigned short*)qkv + (size_t)d * 144 * 768 + h * 32;
    for (int i = threadIdx.x; i < 144 * 32; i += 256) {
        int tt = i >> 5, e = i & 31;
        kS[i] = base[(size_t)tt * 768 + 256 + e];
        vS[i] = base[(size_t)tt * 768 + 512 + e];
    }
    __syncthreads();
    int r = threadIdx.x;
    if (r < 144) {
        float q[32];
        const unsigned short* qp = base + (size_t)r * 768;
#pragma unroll
        for (int e = 0; e < 32; e++) q[e] = __uint_as_float(((unsigned)qp[e]) << 16);
        float mx = -1e30f;
        for (int tp = 0; tp < 144; tp++) {
            const uint4* kp = (const uint4*)&kS[tp * 32];
            float s = 0.f;
#pragma unroll
            for (int u = 0; u < 4; u++) {
                uint4 kv = kp[u];
                s += q[u * 8 + 0] * __uint_as_float(kv.x << 16);
                s += q[u * 8 + 1] * __uint_as_float(kv.x & 0xffff0000u);
                s += q[u * 8 + 2] * __uint_as_float(kv.y << 16);
                s += q[u * 8 + 3] * __uint_as_float(kv.y & 0xffff0000u);
                s += q[u * 8 + 4] * __uint_as_float(kv.z << 16);
                s += q[u * 8 + 5] * __uint_as_float(kv.z & 0xffff0000u);
                s += q[u * 8 + 6] * __uint_as_float(kv.w << 16);
                s += q[u * 8 + 7] * __uint_as_float(kv.w & 0xffff0000u);
            }
            mx = fmaxf(mx, s);
            sS[r * 144 + tp] = s;
        }
        float ov[32];
#pragma unroll
        for (int e = 0; e < 32; e++) ov[e] = 0.f;
        float sum = 0.f;
        for (int tp = 0; tp < 144; tp++) {
            float p = __expf(sS[r * 144 + tp] - mx);
            sum += p;
            const uint4* vp = (const uint4*)&vS[tp * 32];
#pragma unroll
            for (int u = 0; u < 4; u++) {
                uint4 vv = vp[u];
                ov[u * 8 + 0] += p * __uint_as_float(vv.x << 16);
                ov[u * 8 + 1] += p * __uint_as_float(vv.x & 0xffff0000u);
                ov[u * 8 + 2] += p * __uint_as_float(vv.y << 16);
                ov[u * 8 + 3] += p * __uint_as_float(vv.y & 0xffff0000u);
                ov[u * 8 + 4] += p * __uint_as_float(vv.z << 16);
                ov[u * 8 + 5] += p * __uint_as_float(vv.z & 0xffff0000u);
                ov[u * 8 + 6] += p * __uint_as_float(vv.w << 16);
                ov[u * 8 + 7] += p * __uint_as_float(vv.w & 0xffff0000u);
            }
        }
        float inv = 1.f / sum;
        size_t ro = ((size_t)(d * 144 + r)) * 256 + h * 32;
        unsigned short* ohp = (unsigned short*)oh + ro;
        unsigned short* olp = (unsigned short*)ol + ro;
#pragma unroll
        for (int e = 0; e < 32; e++) {
            float val = ov[e] * inv;
            bf16 hi = (bf16)val;
            ohp[e] = __builtin_bit_cast(unsigned short, hi);
            bf16 lo = (bf16)(val - (float)hi);
            olp[e] = __builtin_bit_cast(unsigned short, lo);
        }
    }
}

// ======================= SE gate + scale + pack B^T hi/lo for conv =======================
// kern_f layout: [Co(256)][w(16)][k9(9)][Ci(256)]
// kern_hi/lo layout: [w][Co][k9*256+Ci]  (B^T for conv GEMM), hi+lo = fp32 value
__global__ __launch_bounds__(256) void k_se_scale(const float* __restrict__ kern,
                                                  const float* __restrict__ w1,
                                                  const float* __restrict__ b1,
                                                  const float* __restrict__ w2,
                                                  const float* __restrict__ b2,
                                                  bf16* __restrict__ kern_hi,
                                                  bf16* __restrict__ kern_lo) {
    __shared__ float pooled[256];
    __shared__ float hbuf[16];
    int w = blockIdx.x >> 8, Co = blockIdx.x & 255;
    int ci = threadIdx.x;
    const float* kb = kern + (size_t)(Co * 16 + w) * 9 * 256;
    float pv = 0.f;
#pragma unroll
    for (int k9 = 0; k9 < 9; k9++) pv += kb[k9 * 256 + ci];
    pooled[ci] = pv * (1.f / 9.f);
    __syncthreads();
    if (ci < 16) {
        const float* w1p = w1 + (size_t)(w * 16 + ci) * 256;
        float hs = b1[w * 16 + ci];
        for (int c = 0; c < 256; c++) hs += pooled[c] * w1p[c];
        hbuf[ci] = fmaxf(hs, 0.f);
    }
    __syncthreads();
    const float* w2p = w2 + (size_t)(w * 256 + ci) * 16;
    float ss = b2[w * 256 + ci];
#pragma unroll
    for (int j = 0; j < 16; j++) ss += hbuf[j] * w2p[j];
    float s = 1.f / (1.f + __expf(-ss));
    size_t outo = (size_t)(w * 256 + Co) * 2304;
    bf16* khi = kern_hi + outo;
    bf16* klo = kern_lo + outo;
#pragma unroll
    for (int k9 = 0; k9 < 9; k9++) {
        float f = kb[k9 * 256 + ci] * s;
        bf16 hi = (bf16)f;
        khi[k9 * 256 + ci] = hi;
        klo[k9 * 256 + ci] = (bf16)(f - (float)hi);
    }
}

// ======================= zero fill =======================
__global__ __launch_bounds__(256) void k_zero(uint4* __restrict__ p, int n4) {
    int stride = gridDim.x * 256;
    for (int i = blockIdx.x * 256 + threadIdx.x; i < n4; i += stride)
        p[i] = uint4{0u, 0u, 0u, 0u};
}

// ======================= x -> padded channel-last windows, hi/lo =======================
__global__ __launch_bounds__(256) void k_fill_xcl(const float* __restrict__ x,
                                                  bf16* __restrict__ xcl_h,
                                                  bf16* __restrict__ xcl_l) {
    int bx = blockIdx.x;          // b*64 + gy
    int b = bx >> 6, gy = bx & 63;
    int wrow = gy >> 4, py = gy & 15;
    int ci = threadIdx.x;
    const float* xp = x + ((size_t)(b * 256 + ci) * 64 + gy) * 64;
    for (int wx = 0; wx < 4; wx++) {
        int w = wrow * 4 + wx;
        size_t o = (((size_t)(w * 16 + b) * 18 + py + 1) * 18 + 1) * 256 + ci;
#pragma unroll
        for (int px = 0; px < 16; px++) {
            float f = xp[wx * 16 + px];
            bf16 hi = (bf16)f;
            xcl_h[o + (size_t)px * 256] = hi;
            xcl_l[o + (size_t)px * 256] = (bf16)(f - (float)hi);
        }
    }
}

// ======================= per-window conv as implicit-im2col GEMM (hi/lo A and B) =======================
__global__ __launch_bounds__(256) void k_conv_gemm(const bf16* __restrict__ xcl_h,
                                                   const bf16* __restrict__ xcl_l,
                                                   const bf16* __restrict__ kern_hi,
                                                   const bf16* __restrict__ kern_lo,
                                                   float* __restrict__ y) {
    __shared__ bf16 Ah[128 * 32];
    __shared__ bf16 Al[128 * 32];
    __shared__ bf16 Bh[128 * 32];
    __shared__ bf16 Bl[128 * 32];
    int w = blockIdx.z;
    int m0 = blockIdx.y * 128, n0 = blockIdx.x * 128;
    size_t xwo = (size_t)w * 16 * 18 * 18 * 256;
    const bf16* xwh = xcl_h + xwo;
    const bf16* xwl = xcl_l + xwo;
    const bf16* Bth = kern_hi + (size_t)w * 256 * 2304;
    const bf16* Btl = kern_lo + (size_t)w * 256 * 2304;
    f32x4 acc[4][4] = {};
    int t = threadIdx.x;
    for (int k0 = 0; k0 < 2304; k0 += 32) {
        int k9 = k0 >> 8, ci0 = k0 & 255;
        int dy = k9 / 3, dx = k9 % 3;
#pragma unroll
        for (int c = 0; c < 2; c++) {
            int i = c * 256 + t;
            int row = i >> 2, part = i & 3;
            int m = m0 + row;
            int b = m >> 8, p = m & 255, py = p >> 4, px = p & 15;
            size_t go = ((size_t)(b * 18 + py + dy) * 18 + px + dx) * 256 + ci0 + (part << 3);
            uint4 vh = *(const uint4*)(xwh + go);
            uint4 vl = *(const uint4*)(xwl + go);
            int lo = row * 32 + ((part ^ (row & 3)) << 3);
            *(uint4*)(Ah + lo) = vh;
            *(uint4*)(Al + lo) = vl;
        }
        stage_tile(Bth + (size_t)n0 * 2304 + k0, 2304, Bh);
        stage_tile(Btl + (size_t)n0 * 2304 + k0, 2304, Bl);
        __syncthreads();
        mfma_tile_compute(Ah, Bh, acc);
        mfma_tile_compute(Ah, Bl, acc);
        mfma_tile_compute(Al, Bh, acc);
        __syncthreads();
    }
    int lane = threadIdx.x & 63, wave = threadIdx.x >> 6;
    int wm = (wave >> 1) * 64, wn = (wave & 1) * 64;
    int lrow = lane & 15, quad = lane >> 4;
    float* yw = y + (size_t)w * 4096 * 256;
#pragma unroll
    for (int i = 0; i < 4; i++)
#pragma unroll
        for (int j = 0; j < 4; j++) {
            int col = n0 + wn + j * 16 + lrow;
#pragma unroll
            for (int rr = 0; rr < 4; rr++) {
                int row = m0 + wm + i * 16 + quad * 4 + rr;
                yw[(size_t)row * 256 + col] = acc[i][j][rr];
            }
        }
}

// ======================= layernorm + residual (+window reverse) =======================
__global__ __launch_bounds__(256) void k_ln_res(const float* __restrict__ y,
                                                const float* __restrict__ x,
                                                const float* __restrict__ g,
                                                const float* __restrict__ be,
                                                float* __restrict__ out) {
    int bx = blockIdx.x;          // b*64 + gy
    int b = bx >> 6, gy = bx & 63;
    int t = threadIdx.x;
    int j = t >> 2, sub = t & 3;  // j = gx, sub = channel quarter
    int w = (gy >> 4) * 4 + (j >> 4);
    int p = (gy & 15) * 16 + (j & 15);
    const float* yp = y + ((size_t)w * 4096 + b * 256 + p) * 256 + sub * 64;
    float vals[64];
    float sum = 0.f, sq = 0.f;
#pragma unroll
    for (int c = 0; c < 64; c++) {
        float v = yp[c];
        vals[c] = v;
        sum += v; sq += v * v;
    }
    sum += __shfl_xor(sum, 1); sq += __shfl_xor(sq, 1);
    sum += __shfl_xor(sum, 2); sq += __shfl_xor(sq, 2);
    float mean = sum * (1.f / 256.f);
    float var = sq * (1.f / 256.f) - mean * mean;
    float rstd = rsqrtf(var + 1e-5f);
    const float* xp = x + ((size_t)(b * 256 + sub * 64) * 64 + gy) * 64 + j;
    float* op = out + ((size_t)(b * 256 + sub * 64) * 64 + gy) * 64 + j;
#pragma unroll
    for (int c = 0; c < 64; c++) {
        int cc = sub * 64 + c;
        op[(size_t)c * 4096] = (vals[c] - mean) * rstd * g[cc] + be[cc] + xp[(size_t)c * 4096];
    }
}

// ======================= launch =======================
extern "C" void kernel_launch(void* const* d_in, const int* in_sizes, int n_in,
                              void* d_out, int out_size, void* d_ws, size_t ws_size,
                              hipStream_t stream) {
    const float* x      = (const float*)d_in[0];
    const float* conv_w = (const float*)d_in[1];
    const float* wqkv   = (const float*)d_in[2];
    const float* bqkv   = (const float*)d_in[3];
    const float* wout   = (const float*)d_in[4];
    const float* bout   = (const float*)d_in[5];
    const float* se_w1  = (const float*)d_in[6];
    const float* se_b1  = (const float*)d_in[7];
    const float* se_w2  = (const float*)d_in[8];
    const float* se_b2  = (const float*)d_in[9];
    const float* ln_g   = (const float*)d_in[10];
    const float* ln_b   = (const float*)d_in[11];
    float* out = (float*)d_out;

    // ---- workspace layout (lifetime-overlaid, 190,447,616 B total) ----
    char* ws = (char*)d_ws;
    bf16*  kt      = (bf16*)(ws + 0);             // 18,874,368  kt -> (dead) -> o_h -> kern_hi
    bf16*  o_h     = (bf16*)(ws + 0);
    bf16*  kern_hi = (bf16*)(ws + 0);
    bf16*  o_l     = (bf16*)(ws + 18874368);      // 18,874,368  o_l -> kern_lo
    bf16*  kern_lo = (bf16*)(ws + 18874368);
    bf16*  wqkv_t  = (bf16*)(ws + 37748736);      //    393,216
    bf16*  wout_h  = (bf16*)(ws + 38141952);      //    131,072
    bf16*  wout_l  = (bf16*)(ws + 38273024);      //    131,072
    bf16*  xcl_h   = (bf16*)(ws + 38404096);      // 42,467,328
    bf16*  xcl_l   = (bf16*)(ws + 80871424);      // 42,467,328 (contiguous with xcl_h)
    bf16*  qkv     = (bf16*)(ws + 123338752);     // 56,623,104  qkv -> kern_f -> y
    float* kern_f  = (float*)(ws + 123338752);    // 37,748,736
    float* y       = (float*)(ws + 123338752);    // 67,108,864  (ends at 190,447,616)

    k_prep_w<<<1024, 256, 0, stream>>>(wqkv, wout, wqkv_t, wout_h, wout_l);
    k_build_kt<<<4096, 256, 0, stream>>>(conv_w, kt);
    k_gemm_qkv<<<dim3(6, 288), 256, 0, stream>>>(kt, wqkv_t, bqkv, qkv, 768, 256);
    k_attn<<<2048, 256, 0, stream>>>(qkv, o_h, o_l);
    k_gemm_split3<<<dim3(2, 288), 256, 0, stream>>>(o_h, o_l, wout_h, wout_l, bout, kern_f, 256, 256);
    k_se_scale<<<4096, 256, 0, stream>>>(kern_f, se_w1, se_b1, se_w2, se_b2, kern_hi, kern_lo);
    k_zero<<<2048, 256, 0, stream>>>((uint4*)xcl_h, (42467328 * 2) / 16);
    k_fill_xcl<<<1024, 256, 0, stream>>>(x, xcl_h, xcl_l);
    k_conv_gemm<<<dim3(2, 32, 16), 256, 0, stream>>>(xcl_h, xcl_l, kern_hi, kern_lo, y);
    k_ln_res<<<1024, 256, 0, stream>>>(y, x, ln_g, ln_b, out);
}

// Round 4
// 641.570 us; speedup vs baseline: 1.5958x; 1.5958x over previous
//
#include <hip/hip_runtime.h>

typedef __bf16 bf16;
typedef __bf16 bf16x8 __attribute__((ext_vector_type(8)));
typedef float f32x4 __attribute__((ext_vector_type(4)));

#define SCALE_Q 0.17677669529663687f

// ======================= weight prep (transpose+cast, wout hi/lo) =======================
__global__ __launch_bounds__(256) void k_prep_w(const float* __restrict__ wqkv,
                                                const float* __restrict__ wout,
                                                bf16* __restrict__ wqkv_t,
                                                bf16* __restrict__ wout_h,
                                                bf16* __restrict__ wout_l) {
    int n = blockIdx.x, k = threadIdx.x;
    if (n < 768) {
        wqkv_t[n * 256 + k] = (bf16)wqkv[k * 768 + n];
    } else {
        float f = wout[k * 256 + (n - 768)];
        bf16 hi = (bf16)f;
        wout_h[(n - 768) * 256 + k] = hi;
        wout_l[(n - 768) * 256 + k] = (bf16)(f - (float)hi);
    }
}

// ======================= kt build (permute conv_w) =======================
__global__ __launch_bounds__(256) void k_build_kt(const float* __restrict__ conv_w,
                                                  bf16* __restrict__ kt) {
    __shared__ float lds[2304];
    int w = blockIdx.x >> 8, co = blockIdx.x & 255;
    const float* src = conv_w + (size_t)(w * 256 + co) * 2304;
    for (int i = threadIdx.x; i < 2304; i += 256) lds[i] = src[i];
    __syncthreads();
    int b = co >> 4, c0 = (co & 15) << 4;
    size_t rbase = (size_t)(b * 16 + w) * 144;
    for (int i = threadIdx.x; i < 2304; i += 256) {
        int t = i >> 4, m = i & 15;
        kt[(rbase + t) * 256 + c0 + m] = (bf16)lds[m * 144 + t];
    }
}

// ======================= shared MFMA GEMM pieces =======================
__device__ __forceinline__ void stage_tile(const bf16* __restrict__ gsrc, int ld,
                                           bf16* lds_tile) {
    int t = threadIdx.x;
#pragma unroll
    for (int c = 0; c < 2; c++) {
        int i = c * 256 + t;          // 0..511
        int row = i >> 2, part = i & 3;
        uint4 v = *(const uint4*)(gsrc + (size_t)row * ld + (part << 3));
        *(uint4*)(lds_tile + row * 32 + ((part ^ (row & 3)) << 3)) = v;
    }
}

__device__ __forceinline__ void mfma_tile_compute(const bf16* As, const bf16* Bs,
                                                  f32x4 acc[4][4]) {
    int lane = threadIdx.x & 63;
    int wave = threadIdx.x >> 6;
    int wm = (wave >> 1) * 64, wn = (wave & 1) * 64;
    int lrow = lane & 15, quad = lane >> 4;
    bf16x8 af[4], bfr[4];
#pragma unroll
    for (int i = 0; i < 4; i++) {
        int r = wm + i * 16 + lrow;
        af[i] = *(const bf16x8*)(As + r * 32 + ((quad ^ (r & 3)) << 3));
        int n = wn + i * 16 + lrow;
        bfr[i] = *(const bf16x8*)(Bs + n * 32 + ((quad ^ (n & 3)) << 3));
    }
#pragma unroll
    for (int i = 0; i < 4; i++)
#pragma unroll
        for (int j = 0; j < 4; j++)
            acc[i][j] = __builtin_amdgcn_mfma_f32_16x16x32_bf16(af[i], bfr[j], acc[i][j], 0, 0, 0);
}

// ======================= qkv GEMM: out = A(MxK) * Bt(NxK)^T + bias (bf16 out, q scaled) =======================
__global__ __launch_bounds__(256) void k_gemm_qkv(const bf16* __restrict__ A,
                                                  const bf16* __restrict__ Bt,
                                                  const float* __restrict__ bias,
                                                  bf16* __restrict__ outb,
                                                  int N, int K) {
    __shared__ bf16 As[128 * 32];
    __shared__ bf16 Bs[128 * 32];
    int m0 = blockIdx.y * 128, n0 = blockIdx.x * 128;
    f32x4 acc[4][4] = {};
    for (int k0 = 0; k0 < K; k0 += 32) {
        stage_tile(A + (size_t)m0 * K + k0, K, As);
        stage_tile(Bt + (size_t)n0 * K + k0, K, Bs);
        __syncthreads();
        mfma_tile_compute(As, Bs, acc);
        __syncthreads();
    }
    int lane = threadIdx.x & 63, wave = threadIdx.x >> 6;
    int wm = (wave >> 1) * 64, wn = (wave & 1) * 64;
    int lrow = lane & 15, quad = lane >> 4;
#pragma unroll
    for (int i = 0; i < 4; i++)
#pragma unroll
        for (int j = 0; j < 4; j++) {
            int col = n0 + wn + j * 16 + lrow;
            float bv = bias[col];
#pragma unroll
            for (int rr = 0; rr < 4; rr++) {
                int row = m0 + wm + i * 16 + quad * 4 + rr;
                float v = acc[i][j][rr] + bv;
                if (col < 256) v *= SCALE_Q;
                outb[(size_t)row * N + col] = (bf16)v;
            }
        }
}

// ======================= out-proj GEMM, hi/lo A and B, 3 products, f32 out =======================
__global__ __launch_bounds__(256) void k_gemm_split3(const bf16* __restrict__ Ahg,
                                                     const bf16* __restrict__ Alg,
                                                     const bf16* __restrict__ Bhg,
                                                     const bf16* __restrict__ Blg,
                                                     const float* __restrict__ bias,
                                                     float* __restrict__ outf,
                                                     int N, int K) {
    __shared__ bf16 Ah[128 * 32];
    __shared__ bf16 Al[128 * 32];
    __shared__ bf16 Bh[128 * 32];
    __shared__ bf16 Bl[128 * 32];
    int m0 = blockIdx.y * 128, n0 = blockIdx.x * 128;
    f32x4 acc[4][4] = {};
    for (int k0 = 0; k0 < K; k0 += 32) {
        stage_tile(Ahg + (size_t)m0 * K + k0, K, Ah);
        stage_tile(Alg + (size_t)m0 * K + k0, K, Al);
        stage_tile(Bhg + (size_t)n0 * K + k0, K, Bh);
        stage_tile(Blg + (size_t)n0 * K + k0, K, Bl);
        __syncthreads();
        mfma_tile_compute(Ah, Bh, acc);
        mfma_tile_compute(Ah, Bl, acc);
        mfma_tile_compute(Al, Bh, acc);
        __syncthreads();
    }
    int lane = threadIdx.x & 63, wave = threadIdx.x >> 6;
    int wm = (wave >> 1) * 64, wn = (wave & 1) * 64;
    int lrow = lane & 15, quad = lane >> 4;
#pragma unroll
    for (int i = 0; i < 4; i++)
#pragma unroll
        for (int j = 0; j < 4; j++) {
            int col = n0 + wn + j * 16 + lrow;
            float bv = bias[col];
#pragma unroll
            for (int rr = 0; rr < 4; rr++) {
                int row = m0 + wm + i * 16 + quad * 4 + rr;
                outf[(size_t)row * N + col] = acc[i][j][rr] + bv;
            }
        }
}

// ======================= attention: MFMA flash-style per (d,h) block =======================
// Q,K staged swizzled [144][32]; V transposed [e 0..31][t 0..159] zero-padded;
// per-wave P buffer [16][168] (stride 168 = 336B keeps 16B alignment, 4-way max conflict).
__global__ __launch_bounds__(256) void k_attn(const bf16* __restrict__ qkv,
                                              bf16* __restrict__ oh,
                                              bf16* __restrict__ ol) {
    __shared__ bf16 Qs[144 * 32];
    __shared__ bf16 Ks[144 * 32];
    __shared__ bf16 Vt[32 * 160];
    __shared__ bf16 Ps[4 * 16 * 168];
    int d = blockIdx.x >> 3, h = blockIdx.x & 7;
    const bf16* base = qkv + (size_t)d * 144 * 768 + h * 32;
    int t = threadIdx.x;

    // zero Vt pad cols 144..159
    for (int i = t; i < 512; i += 256) Vt[(i >> 4) * 160 + 144 + (i & 15)] = (bf16)0.f;
    // stage Q, K (xor-swizzled rows of 32), V transposed
    for (int i = t; i < 576; i += 256) {     // 144 rows * 4 parts
        int row = i >> 2, part = i & 3;
        const bf16* rp = base + (size_t)row * 768;
        uint4 vq = *(const uint4*)(rp + (part << 3));
        uint4 vk = *(const uint4*)(rp + 256 + (part << 3));
        int sw = ((part ^ (row & 3)) << 3);
        *(uint4*)(Qs + row * 32 + sw) = vq;
        *(uint4*)(Ks + row * 32 + sw) = vk;
        bf16x8 v8 = *(const bf16x8*)(rp + 512 + (part << 3));
#pragma unroll
        for (int j = 0; j < 8; j++) Vt[(part * 8 + j) * 160 + row] = v8[j];
    }
    __syncthreads();

    int wave = t >> 6, lane = t & 63;
    int lrow = lane & 15, quad = lane >> 4;
    bf16* Pw = Ps + wave * 16 * 168;
    // zero own P pad cols 144..159
    for (int i = lane; i < 256; i += 64) Pw[(i >> 4) * 168 + 144 + (i & 15)] = (bf16)0.f;

    // preload all 9 K fragments (held across m-tiles)
    bf16x8 kf[9];
#pragma unroll
    for (int nt = 0; nt < 9; nt++) {
        int r = nt * 16 + lrow;
        kf[nt] = *(const bf16x8*)(Ks + r * 32 + ((quad ^ (r & 3)) << 3));
    }

    for (int mt = wave; mt < 9; mt += 4) {
        int qr = mt * 16 + lrow;
        bf16x8 qf = *(const bf16x8*)(Qs + qr * 32 + ((quad ^ (qr & 3)) << 3));
        f32x4 s[9];
#pragma unroll
        for (int nt = 0; nt < 9; nt++) {
            f32x4 z = {0.f, 0.f, 0.f, 0.f};
            s[nt] = __builtin_amdgcn_mfma_f32_16x16x32_bf16(qf, kf[nt], z, 0, 0, 0);
        }
        // row max over 144 cols: 9 accs then 16-lane shuffle tree
        f32x4 mx = s[0];
#pragma unroll
        for (int nt = 1; nt < 9; nt++)
#pragma unroll
            for (int c = 0; c < 4; c++) mx[c] = fmaxf(mx[c], s[nt][c]);
#pragma unroll
        for (int off = 1; off < 16; off <<= 1)
#pragma unroll
            for (int c = 0; c < 4; c++) mx[c] = fmaxf(mx[c], __shfl_xor(mx[c], off));
        // exp + sum
        f32x4 sm = {0.f, 0.f, 0.f, 0.f};
#pragma unroll
        for (int nt = 0; nt < 9; nt++)
#pragma unroll
            for (int c = 0; c < 4; c++) {
                float e = __expf(s[nt][c] - mx[c]);
                s[nt][c] = e;
                sm[c] += e;
            }
#pragma unroll
        for (int off = 1; off < 16; off <<= 1)
#pragma unroll
            for (int c = 0; c < 4; c++) sm[c] += __shfl_xor(sm[c], off);
        f32x4 inv;
#pragma unroll
        for (int c = 0; c < 4; c++) inv[c] = 1.f / sm[c];
        // write normalized P (bf16) into own LDS buffer: row=quad*4+c, col=nt*16+lrow
#pragma unroll
        for (int nt = 0; nt < 9; nt++)
#pragma unroll
            for (int c = 0; c < 4; c++)
                Pw[(quad * 4 + c) * 168 + nt * 16 + lrow] = (bf16)(s[nt][c] * inv[c]);

        // PV: O-tile 16x32, 5 zero-padded k-tiles
        f32x4 o0 = {0.f, 0.f, 0.f, 0.f}, o1 = {0.f, 0.f, 0.f, 0.f};
#pragma unroll
        for (int kt = 0; kt < 5; kt++) {
            bf16x8 pf = *(const bf16x8*)(Pw + lrow * 168 + kt * 32 + quad * 8);
            bf16x8 v0 = *(const bf16x8*)(Vt + lrow * 160 + kt * 32 + quad * 8);
            bf16x8 v1 = *(const bf16x8*)(Vt + (16 + lrow) * 160 + kt * 32 + quad * 8);
            o0 = __builtin_amdgcn_mfma_f32_16x16x32_bf16(pf, v0, o0, 0, 0, 0);
            o1 = __builtin_amdgcn_mfma_f32_16x16x32_bf16(pf, v1, o1, 0, 0, 0);
        }
        // write O hi/lo: row q = mt*16+quad*4+c, e = lrow / 16+lrow
        size_t ro = ((size_t)d * 144 + mt * 16) * 256 + h * 32;
#pragma unroll
        for (int c = 0; c < 4; c++) {
            size_t rr = ro + (size_t)(quad * 4 + c) * 256;
            float v = o0[c];
            bf16 hi = (bf16)v;
            oh[rr + lrow] = hi;
            ol[rr + lrow] = (bf16)(v - (float)hi);
            v = o1[c];
            hi = (bf16)v;
            oh[rr + 16 + lrow] = hi;
            ol[rr + 16 + lrow] = (bf16)(v - (float)hi);
        }
    }
}

// ======================= SE gate + scale + pack B^T hi/lo for conv =======================
// kern_f layout: [Co(256)][w(16)][k9(9)][Ci(256)]
// kern_hi/lo layout: [w][Co][k9*256+Ci]  (B^T for conv GEMM), hi+lo = fp32 value
__global__ __launch_bounds__(256) void k_se_scale(const float* __restrict__ kern,
                                                  const float* __restrict__ w1,
                                                  const float* __restrict__ b1,
                                                  const float* __restrict__ w2,
                                                  const float* __restrict__ b2,
                                                  bf16* __restrict__ kern_hi,
                                                  bf16* __restrict__ kern_lo) {
    __shared__ float pooled[256];
    __shared__ float hbuf[16];
    int w = blockIdx.x >> 8, Co = blockIdx.x & 255;
    int ci = threadIdx.x;
    const float* kb = kern + (size_t)(Co * 16 + w) * 9 * 256;
    float pv = 0.f;
#pragma unroll
    for (int k9 = 0; k9 < 9; k9++) pv += kb[k9 * 256 + ci];
    pooled[ci] = pv * (1.f / 9.f);
    __syncthreads();
    if (ci < 16) {
        const float* w1p = w1 + (size_t)(w * 16 + ci) * 256;
        float hs = b1[w * 16 + ci];
        for (int c = 0; c < 256; c++) hs += pooled[c] * w1p[c];
        hbuf[ci] = fmaxf(hs, 0.f);
    }
    __syncthreads();
    const float* w2p = w2 + (size_t)(w * 256 + ci) * 16;
    float ss = b2[w * 256 + ci];
#pragma unroll
    for (int j = 0; j < 16; j++) ss += hbuf[j] * w2p[j];
    float s = 1.f / (1.f + __expf(-ss));
    size_t outo = (size_t)(w * 256 + Co) * 2304;
    bf16* khi = kern_hi + outo;
    bf16* klo = kern_lo + outo;
#pragma unroll
    for (int k9 = 0; k9 < 9; k9++) {
        float f = kb[k9 * 256 + ci] * s;
        bf16 hi = (bf16)f;
        khi[k9 * 256 + ci] = hi;
        klo[k9 * 256 + ci] = (bf16)(f - (float)hi);
    }
}

// ======================= zero fill =======================
__global__ __launch_bounds__(256) void k_zero(uint4* __restrict__ p, int n4) {
    int stride = gridDim.x * 256;
    for (int i = blockIdx.x * 256 + threadIdx.x; i < n4; i += stride)
        p[i] = uint4{0u, 0u, 0u, 0u};
}

// ======================= x -> padded channel-last windows, hi/lo =======================
__global__ __launch_bounds__(256) void k_fill_xcl(const float* __restrict__ x,
                                                  bf16* __restrict__ xcl_h,
                                                  bf16* __restrict__ xcl_l) {
    int bx = blockIdx.x;          // b*64 + gy
    int b = bx >> 6, gy = bx & 63;
    int wrow = gy >> 4, py = gy & 15;
    int ci = threadIdx.x;
    const float* xp = x + ((size_t)(b * 256 + ci) * 64 + gy) * 64;
    for (int wx = 0; wx < 4; wx++) {
        int w = wrow * 4 + wx;
        size_t o = (((size_t)(w * 16 + b) * 18 + py + 1) * 18 + 1) * 256 + ci;
#pragma unroll
        for (int px = 0; px < 16; px++) {
            float f = xp[wx * 16 + px];
            bf16 hi = (bf16)f;
            xcl_h[o + (size_t)px * 256] = hi;
            xcl_l[o + (size_t)px * 256] = (bf16)(f - (float)hi);
        }
    }
}

// ======================= per-window conv as implicit-im2col GEMM (hi/lo A and B) =======================
__global__ __launch_bounds__(256) void k_conv_gemm(const bf16* __restrict__ xcl_h,
                                                   const bf16* __restrict__ xcl_l,
                                                   const bf16* __restrict__ kern_hi,
                                                   const bf16* __restrict__ kern_lo,
                                                   float* __restrict__ y) {
    __shared__ bf16 Ah[128 * 32];
    __shared__ bf16 Al[128 * 32];
    __shared__ bf16 Bh[128 * 32];
    __shared__ bf16 Bl[128 * 32];
    int w = blockIdx.z;
    int m0 = blockIdx.y * 128, n0 = blockIdx.x * 128;
    size_t xwo = (size_t)w * 16 * 18 * 18 * 256;
    const bf16* xwh = xcl_h + xwo;
    const bf16* xwl = xcl_l + xwo;
    const bf16* Bth = kern_hi + (size_t)w * 256 * 2304;
    const bf16* Btl = kern_lo + (size_t)w * 256 * 2304;
    f32x4 acc[4][4] = {};
    int t = threadIdx.x;
    for (int k0 = 0; k0 < 2304; k0 += 32) {
        int k9 = k0 >> 8, ci0 = k0 & 255;
        int dy = k9 / 3, dx = k9 % 3;
#pragma unroll
        for (int c = 0; c < 2; c++) {
            int i = c * 256 + t;
            int row = i >> 2, part = i & 3;
            int m = m0 + row;
            int b = m >> 8, p = m & 255, py = p >> 4, px = p & 15;
            size_t go = ((size_t)(b * 18 + py + dy) * 18 + px + dx) * 256 + ci0 + (part << 3);
            uint4 vh = *(const uint4*)(xwh + go);
            uint4 vl = *(const uint4*)(xwl + go);
            int lo = row * 32 + ((part ^ (row & 3)) << 3);
            *(uint4*)(Ah + lo) = vh;
            *(uint4*)(Al + lo) = vl;
        }
        stage_tile(Bth + (size_t)n0 * 2304 + k0, 2304, Bh);
        stage_tile(Btl + (size_t)n0 * 2304 + k0, 2304, Bl);
        __syncthreads();
        mfma_tile_compute(Ah, Bh, acc);
        mfma_tile_compute(Ah, Bl, acc);
        mfma_tile_compute(Al, Bh, acc);
        __syncthreads();
    }
    int lane = threadIdx.x & 63, wave = threadIdx.x >> 6;
    int wm = (wave >> 1) * 64, wn = (wave & 1) * 64;
    int lrow = lane & 15, quad = lane >> 4;
    float* yw = y + (size_t)w * 4096 * 256;
#pragma unroll
    for (int i = 0; i < 4; i++)
#pragma unroll
        for (int j = 0; j < 4; j++) {
            int col = n0 + wn + j * 16 + lrow;
#pragma unroll
            for (int rr = 0; rr < 4; rr++) {
                int row = m0 + wm + i * 16 + quad * 4 + rr;
                yw[(size_t)row * 256 + col] = acc[i][j][rr];
            }
        }
}

// ======================= layernorm + residual (+window reverse) =======================
__global__ __launch_bounds__(256) void k_ln_res(const float* __restrict__ y,
                                                const float* __restrict__ x,
                                                const float* __restrict__ g,
                                                const float* __restrict__ be,
                                                float* __restrict__ out) {
    int bx = blockIdx.x;          // b*64 + gy
    int b = bx >> 6, gy = bx & 63;
    int t = threadIdx.x;
    int j = t >> 2, sub = t & 3;  // j = gx, sub = channel quarter
    int w = (gy >> 4) * 4 + (j >> 4);
    int p = (gy & 15) * 16 + (j & 15);
    const float* yp = y + ((size_t)w * 4096 + b * 256 + p) * 256 + sub * 64;
    float vals[64];
    float sum = 0.f, sq = 0.f;
#pragma unroll
    for (int c = 0; c < 64; c++) {
        float v = yp[c];
        vals[c] = v;
        sum += v; sq += v * v;
    }
    sum += __shfl_xor(sum, 1); sq += __shfl_xor(sq, 1);
    sum += __shfl_xor(sum, 2); sq += __shfl_xor(sq, 2);
    float mean = sum * (1.f / 256.f);
    float var = sq * (1.f / 256.f) - mean * mean;
    float rstd = rsqrtf(var + 1e-5f);
    const float* xp = x + ((size_t)(b * 256 + sub * 64) * 64 + gy) * 64 + j;
    float* op = out + ((size_t)(b * 256 + sub * 64) * 64 + gy) * 64 + j;
#pragma unroll
    for (int c = 0; c < 64; c++) {
        int cc = sub * 64 + c;
        op[(size_t)c * 4096] = (vals[c] - mean) * rstd * g[cc] + be[cc] + xp[(size_t)c * 4096];
    }
}

// ======================= launch =======================
extern "C" void kernel_launch(void* const* d_in, const int* in_sizes, int n_in,
                              void* d_out, int out_size, void* d_ws, size_t ws_size,
                              hipStream_t stream) {
    const float* x      = (const float*)d_in[0];
    const float* conv_w = (const float*)d_in[1];
    const float* wqkv   = (const float*)d_in[2];
    const float* bqkv   = (const float*)d_in[3];
    const float* wout   = (const float*)d_in[4];
    const float* bout   = (const float*)d_in[5];
    const float* se_w1  = (const float*)d_in[6];
    const float* se_b1  = (const float*)d_in[7];
    const float* se_w2  = (const float*)d_in[8];
    const float* se_b2  = (const float*)d_in[9];
    const float* ln_g   = (const float*)d_in[10];
    const float* ln_b   = (const float*)d_in[11];
    float* out = (float*)d_out;

    // ---- workspace layout (lifetime-overlaid, 190,447,616 B total) ----
    char* ws = (char*)d_ws;
    bf16*  kt      = (bf16*)(ws + 0);             // 18,874,368  kt -> (dead) -> o_h -> kern_hi
    bf16*  o_h     = (bf16*)(ws + 0);
    bf16*  kern_hi = (bf16*)(ws + 0);
    bf16*  o_l     = (bf16*)(ws + 18874368);      // 18,874,368  o_l -> kern_lo
    bf16*  kern_lo = (bf16*)(ws + 18874368);
    bf16*  wqkv_t  = (bf16*)(ws + 37748736);      //    393,216
    bf16*  wout_h  = (bf16*)(ws + 38141952);      //    131,072
    bf16*  wout_l  = (bf16*)(ws + 38273024);      //    131,072
    bf16*  xcl_h   = (bf16*)(ws + 38404096);      // 42,467,328
    bf16*  xcl_l   = (bf16*)(ws + 80871424);      // 42,467,328 (contiguous with xcl_h)
    bf16*  qkv     = (bf16*)(ws + 123338752);     // 56,623,104  qkv -> kern_f -> y
    float* kern_f  = (float*)(ws + 123338752);    // 37,748,736
    float* y       = (float*)(ws + 123338752);    // 67,108,864  (ends at 190,447,616)

    k_prep_w<<<1024, 256, 0, stream>>>(wqkv, wout, wqkv_t, wout_h, wout_l);
    k_build_kt<<<4096, 256, 0, stream>>>(conv_w, kt);
    k_gemm_qkv<<<dim3(6, 288), 256, 0, stream>>>(kt, wqkv_t, bqkv, qkv, 768, 256);
    k_attn<<<2048, 256, 0, stream>>>(qkv, o_h, o_l);
    k_gemm_split3<<<dim3(2, 288), 256, 0, stream>>>(o_h, o_l, wout_h, wout_l, bout, kern_f, 256, 256);
    k_se_scale<<<4096, 256, 0, stream>>>(kern_f, se_w1, se_b1, se_w2, se_b2, kern_hi, kern_lo);
    k_zero<<<2048, 256, 0, stream>>>((uint4*)xcl_h, (42467328 * 2) / 16);
    k_fill_xcl<<<1024, 256, 0, stream>>>(x, xcl_h, xcl_l);
    k_conv_gemm<<<dim3(2, 32, 16), 256, 0, stream>>>(xcl_h, xcl_l, kern_hi, kern_lo, y);
    k_ln_res<<<1024, 256, 0, stream>>>(y, x, ln_g, ln_b, out);
}

// Round 5
// 554.472 us; speedup vs baseline: 1.8464x; 1.1571x over previous
//
#include <hip/hip_runtime.h>

typedef __bf16 bf16;
typedef __bf16 bf16x8 __attribute__((ext_vector_type(8)));
typedef _Float16 f16;
typedef _Float16 f16x8 __attribute__((ext_vector_type(8)));
typedef float f32x4 __attribute__((ext_vector_type(4)));

#define SCALE_Q 0.17677669529663687f
#define KSCALE 64.0f
#define KSCALE_INV 0.015625f

// ======================= weight prep: wqkv^T bf16; wout^T fp16 hi/lo (x64) =======================
__global__ __launch_bounds__(256) void k_prep_w(const float* __restrict__ wqkv,
                                                const float* __restrict__ wout,
                                                bf16* __restrict__ wqkv_t,
                                                f16* __restrict__ wout_h,
                                                f16* __restrict__ wout_l) {
    int n = blockIdx.x, k = threadIdx.x;
    if (n < 768) {
        wqkv_t[n * 256 + k] = (bf16)wqkv[k * 768 + n];
    } else {
        float f = wout[k * 256 + (n - 768)] * KSCALE;
        f16 hi = (f16)f;
        wout_h[(n - 768) * 256 + k] = hi;
        wout_l[(n - 768) * 256 + k] = (f16)(f - (float)hi);
    }
}

// ======================= kt build (permute conv_w) =======================
__global__ __launch_bounds__(256) void k_build_kt(const float* __restrict__ conv_w,
                                                  bf16* __restrict__ kt) {
    __shared__ float lds[2304];
    int w = blockIdx.x >> 8, co = blockIdx.x & 255;
    const float* src = conv_w + (size_t)(w * 256 + co) * 2304;
    for (int i = threadIdx.x; i < 2304; i += 256) lds[i] = src[i];
    __syncthreads();
    int b = co >> 4, c0 = (co & 15) << 4;
    size_t rbase = (size_t)(b * 16 + w) * 144;
    for (int i = threadIdx.x; i < 2304; i += 256) {
        int t = i >> 4, m = i & 15;
        kt[(rbase + t) * 256 + c0 + m] = (bf16)lds[m * 144 + t];
    }
}

// ======================= shared MFMA GEMM pieces (dtype-agnostic 2B staging) =======================
__device__ __forceinline__ void stage_tile(const void* __restrict__ gsrc_, int ld,
                                           void* lds_) {
    const unsigned short* gsrc = (const unsigned short*)gsrc_;
    unsigned short* lds_tile = (unsigned short*)lds_;
    int t = threadIdx.x;
#pragma unroll
    for (int c = 0; c < 2; c++) {
        int i = c * 256 + t;          // 0..511
        int row = i >> 2, part = i & 3;
        uint4 v = *(const uint4*)(gsrc + (size_t)row * ld + (part << 3));
        *(uint4*)(lds_tile + row * 32 + ((part ^ (row & 3)) << 3)) = v;
    }
}

__device__ __forceinline__ void mfma_tile_bf16(const bf16* As, const bf16* Bs,
                                               f32x4 acc[4][4]) {
    int lane = threadIdx.x & 63;
    int wave = threadIdx.x >> 6;
    int wm = (wave >> 1) * 64, wn = (wave & 1) * 64;
    int lrow = lane & 15, quad = lane >> 4;
    bf16x8 af[4], bfr[4];
#pragma unroll
    for (int i = 0; i < 4; i++) {
        int r = wm + i * 16 + lrow;
        af[i] = *(const bf16x8*)(As + r * 32 + ((quad ^ (r & 3)) << 3));
        int n = wn + i * 16 + lrow;
        bfr[i] = *(const bf16x8*)(Bs + n * 32 + ((quad ^ (n & 3)) << 3));
    }
#pragma unroll
    for (int i = 0; i < 4; i++)
#pragma unroll
        for (int j = 0; j < 4; j++)
            acc[i][j] = __builtin_amdgcn_mfma_f32_16x16x32_bf16(af[i], bfr[j], acc[i][j], 0, 0, 0);
}

__device__ __forceinline__ void mfma_tile_f16(const f16* As, const f16* Bs,
                                              f32x4 acc[4][4]) {
    int lane = threadIdx.x & 63;
    int wave = threadIdx.x >> 6;
    int wm = (wave >> 1) * 64, wn = (wave & 1) * 64;
    int lrow = lane & 15, quad = lane >> 4;
    f16x8 af[4], bfr[4];
#pragma unroll
    for (int i = 0; i < 4; i++) {
        int r = wm + i * 16 + lrow;
        af[i] = *(const f16x8*)(As + r * 32 + ((quad ^ (r & 3)) << 3));
        int n = wn + i * 16 + lrow;
        bfr[i] = *(const f16x8*)(Bs + n * 32 + ((quad ^ (n & 3)) << 3));
    }
#pragma unroll
    for (int i = 0; i < 4; i++)
#pragma unroll
        for (int j = 0; j < 4; j++)
            acc[i][j] = __builtin_amdgcn_mfma_f32_16x16x32_f16(af[i], bfr[j], acc[i][j], 0, 0, 0);
}

// ======================= qkv GEMM (bf16) =======================
__global__ __launch_bounds__(256) void k_gemm_qkv(const bf16* __restrict__ A,
                                                  const bf16* __restrict__ Bt,
                                                  const float* __restrict__ bias,
                                                  bf16* __restrict__ outb,
                                                  int N, int K) {
    __shared__ bf16 As[128 * 32];
    __shared__ bf16 Bs[128 * 32];
    int m0 = blockIdx.y * 128, n0 = blockIdx.x * 128;
    f32x4 acc[4][4] = {};
    for (int k0 = 0; k0 < K; k0 += 32) {
        stage_tile(A + (size_t)m0 * K + k0, K, As);
        stage_tile(Bt + (size_t)n0 * K + k0, K, Bs);
        __syncthreads();
        mfma_tile_bf16(As, Bs, acc);
        __syncthreads();
    }
    int lane = threadIdx.x & 63, wave = threadIdx.x >> 6;
    int wm = (wave >> 1) * 64, wn = (wave & 1) * 64;
    int lrow = lane & 15, quad = lane >> 4;
#pragma unroll
    for (int i = 0; i < 4; i++)
#pragma unroll
        for (int j = 0; j < 4; j++) {
            int col = n0 + wn + j * 16 + lrow;
            float bv = bias[col];
#pragma unroll
            for (int rr = 0; rr < 4; rr++) {
                int row = m0 + wm + i * 16 + quad * 4 + rr;
                float v = acc[i][j][rr] + bv;
                if (col < 256) v *= SCALE_Q;
                outb[(size_t)row * N + col] = (bf16)v;
            }
        }
}

// ======================= out-proj GEMM: A fp16 single, B fp16 hi/lo (x64), 2 products =======================
__global__ __launch_bounds__(256) void k_gemm_split2(const f16* __restrict__ Ag,
                                                     const f16* __restrict__ Bhg,
                                                     const f16* __restrict__ Blg,
                                                     const float* __restrict__ bias,
                                                     float* __restrict__ outf,
                                                     int N, int K) {
    __shared__ f16 As[128 * 32];
    __shared__ f16 Bh[128 * 32];
    __shared__ f16 Bl[128 * 32];
    int m0 = blockIdx.y * 128, n0 = blockIdx.x * 128;
    f32x4 acc[4][4] = {};
    for (int k0 = 0; k0 < K; k0 += 32) {
        stage_tile(Ag + (size_t)m0 * K + k0, K, As);
        stage_tile(Bhg + (size_t)n0 * K + k0, K, Bh);
        stage_tile(Blg + (size_t)n0 * K + k0, K, Bl);
        __syncthreads();
        mfma_tile_f16(As, Bh, acc);
        mfma_tile_f16(As, Bl, acc);
        __syncthreads();
    }
    int lane = threadIdx.x & 63, wave = threadIdx.x >> 6;
    int wm = (wave >> 1) * 64, wn = (wave & 1) * 64;
    int lrow = lane & 15, quad = lane >> 4;
#pragma unroll
    for (int i = 0; i < 4; i++)
#pragma unroll
        for (int j = 0; j < 4; j++) {
            int col = n0 + wn + j * 16 + lrow;
            float bv = bias[col];
#pragma unroll
            for (int rr = 0; rr < 4; rr++) {
                int row = m0 + wm + i * 16 + quad * 4 + rr;
                outf[(size_t)row * N + col] = acc[i][j][rr] * KSCALE_INV + bv;
            }
        }
}

// ======================= attention: MFMA flash-style per (d,h) block =======================
// Q,K bf16 swizzled [144][32]; V transposed fp16 [32][160] zero-padded;
// per-wave P fp16 [16][168]; O stored fp16 single.
__global__ __launch_bounds__(256) void k_attn(const bf16* __restrict__ qkv,
                                              f16* __restrict__ o16) {
    __shared__ bf16 Qs[144 * 32];
    __shared__ bf16 Ks[144 * 32];
    __shared__ f16 Vt[32 * 160];
    __shared__ f16 Ps[4 * 16 * 168];
    int d = blockIdx.x >> 3, h = blockIdx.x & 7;
    const bf16* base = qkv + (size_t)d * 144 * 768 + h * 32;
    int t = threadIdx.x;

    for (int i = t; i < 512; i += 256) Vt[(i >> 4) * 160 + 144 + (i & 15)] = (f16)0.f;
    for (int i = t; i < 576; i += 256) {     // 144 rows * 4 parts
        int row = i >> 2, part = i & 3;
        const bf16* rp = base + (size_t)row * 768;
        uint4 vq = *(const uint4*)(rp + (part << 3));
        uint4 vk = *(const uint4*)(rp + 256 + (part << 3));
        int sw = ((part ^ (row & 3)) << 3);
        *(uint4*)(Qs + row * 32 + sw) = vq;
        *(uint4*)(Ks + row * 32 + sw) = vk;
        bf16x8 v8 = *(const bf16x8*)(rp + 512 + (part << 3));
#pragma unroll
        for (int j = 0; j < 8; j++) Vt[(part * 8 + j) * 160 + row] = (f16)(float)v8[j];
    }
    __syncthreads();

    int wave = t >> 6, lane = t & 63;
    int lrow = lane & 15, quad = lane >> 4;
    f16* Pw = Ps + wave * 16 * 168;
    for (int i = lane; i < 256; i += 64) Pw[(i >> 4) * 168 + 144 + (i & 15)] = (f16)0.f;

    bf16x8 kf[9];
#pragma unroll
    for (int nt = 0; nt < 9; nt++) {
        int r = nt * 16 + lrow;
        kf[nt] = *(const bf16x8*)(Ks + r * 32 + ((quad ^ (r & 3)) << 3));
    }

    for (int mt = wave; mt < 9; mt += 4) {
        int qr = mt * 16 + lrow;
        bf16x8 qf = *(const bf16x8*)(Qs + qr * 32 + ((quad ^ (qr & 3)) << 3));
        f32x4 s[9];
#pragma unroll
        for (int nt = 0; nt < 9; nt++) {
            f32x4 z = {0.f, 0.f, 0.f, 0.f};
            s[nt] = __builtin_amdgcn_mfma_f32_16x16x32_bf16(qf, kf[nt], z, 0, 0, 0);
        }
        f32x4 mx = s[0];
#pragma unroll
        for (int nt = 1; nt < 9; nt++)
#pragma unroll
            for (int c = 0; c < 4; c++) mx[c] = fmaxf(mx[c], s[nt][c]);
#pragma unroll
        for (int off = 1; off < 16; off <<= 1)
#pragma unroll
            for (int c = 0; c < 4; c++) mx[c] = fmaxf(mx[c], __shfl_xor(mx[c], off));
        f32x4 sm = {0.f, 0.f, 0.f, 0.f};
#pragma unroll
        for (int nt = 0; nt < 9; nt++)
#pragma unroll
            for (int c = 0; c < 4; c++) {
                float e = __expf(s[nt][c] - mx[c]);
                s[nt][c] = e;
                sm[c] += e;
            }
#pragma unroll
        for (int off = 1; off < 16; off <<= 1)
#pragma unroll
            for (int c = 0; c < 4; c++) sm[c] += __shfl_xor(sm[c], off);
        f32x4 inv;
#pragma unroll
        for (int c = 0; c < 4; c++) inv[c] = 1.f / sm[c];
#pragma unroll
        for (int nt = 0; nt < 9; nt++)
#pragma unroll
            for (int c = 0; c < 4; c++)
                Pw[(quad * 4 + c) * 168 + nt * 16 + lrow] = (f16)(s[nt][c] * inv[c]);

        f32x4 o0 = {0.f, 0.f, 0.f, 0.f}, o1 = {0.f, 0.f, 0.f, 0.f};
#pragma unroll
        for (int kt = 0; kt < 5; kt++) {
            f16x8 pf = *(const f16x8*)(Pw + lrow * 168 + kt * 32 + quad * 8);
            f16x8 v0 = *(const f16x8*)(Vt + lrow * 160 + kt * 32 + quad * 8);
            f16x8 v1 = *(const f16x8*)(Vt + (16 + lrow) * 160 + kt * 32 + quad * 8);
            o0 = __builtin_amdgcn_mfma_f32_16x16x32_f16(pf, v0, o0, 0, 0, 0);
            o1 = __builtin_amdgcn_mfma_f32_16x16x32_f16(pf, v1, o1, 0, 0, 0);
        }
        size_t ro = ((size_t)d * 144 + mt * 16) * 256 + h * 32;
#pragma unroll
        for (int c = 0; c < 4; c++) {
            size_t rr = ro + (size_t)(quad * 4 + c) * 256;
            o16[rr + lrow] = (f16)o0[c];
            o16[rr + 16 + lrow] = (f16)o1[c];
        }
    }
}

// ======================= SE gate + scale + pack B^T fp16 hi/lo (x64) for conv =======================
// kern_f layout: [Co(256)][w(16)][k9(9)][Ci(256)]
// kern_hi/lo layout: [w][Co][k9*256+Ci]
__global__ __launch_bounds__(256) void k_se_scale(const float* __restrict__ kern,
                                                  const float* __restrict__ w1,
                                                  const float* __restrict__ b1,
                                                  const float* __restrict__ w2,
                                                  const float* __restrict__ b2,
                                                  f16* __restrict__ kern_hi,
                                                  f16* __restrict__ kern_lo) {
    __shared__ float pooled[256];
    __shared__ float hbuf[16];
    int w = blockIdx.x >> 8, Co = blockIdx.x & 255;
    int ci = threadIdx.x;
    const float* kb = kern + (size_t)(Co * 16 + w) * 9 * 256;
    float pv = 0.f;
#pragma unroll
    for (int k9 = 0; k9 < 9; k9++) pv += kb[k9 * 256 + ci];
    pooled[ci] = pv * (1.f / 9.f);
    __syncthreads();
    if (ci < 16) {
        const float* w1p = w1 + (size_t)(w * 16 + ci) * 256;
        float hs = b1[w * 16 + ci];
        for (int c = 0; c < 256; c++) hs += pooled[c] * w1p[c];
        hbuf[ci] = fmaxf(hs, 0.f);
    }
    __syncthreads();
    const float* w2p = w2 + (size_t)(w * 256 + ci) * 16;
    float ss = b2[w * 256 + ci];
#pragma unroll
    for (int j = 0; j < 16; j++) ss += hbuf[j] * w2p[j];
    float s = (1.f / (1.f + __expf(-ss))) * KSCALE;
    size_t outo = (size_t)(w * 256 + Co) * 2304;
    f16* khi = kern_hi + outo;
    f16* klo = kern_lo + outo;
#pragma unroll
    for (int k9 = 0; k9 < 9; k9++) {
        float f = kb[k9 * 256 + ci] * s;
        f16 hi = (f16)f;
        khi[k9 * 256 + ci] = hi;
        klo[k9 * 256 + ci] = (f16)(f - (float)hi);
    }
}

// ======================= zero fill =======================
__global__ __launch_bounds__(256) void k_zero(uint4* __restrict__ p, int n4) {
    int stride = gridDim.x * 256;
    for (int i = blockIdx.x * 256 + threadIdx.x; i < n4; i += stride)
        p[i] = uint4{0u, 0u, 0u, 0u};
}

// ======================= x -> padded channel-last windows, fp16 single =======================
__global__ __launch_bounds__(256) void k_fill_xcl(const float* __restrict__ x,
                                                  f16* __restrict__ xcl) {
    int bx = blockIdx.x;          // b*64 + gy
    int b = bx >> 6, gy = bx & 63;
    int wrow = gy >> 4, py = gy & 15;
    int ci = threadIdx.x;
    const float* xp = x + ((size_t)(b * 256 + ci) * 64 + gy) * 64;
    for (int wx = 0; wx < 4; wx++) {
        int w = wrow * 4 + wx;
        size_t o = (((size_t)(w * 16 + b) * 18 + py + 1) * 18 + 1) * 256 + ci;
#pragma unroll
        for (int px = 0; px < 16; px++)
            xcl[o + (size_t)px * 256] = (f16)xp[wx * 16 + px];
    }
}

// ======================= per-window conv as implicit-im2col GEMM (fp16, 2 products) =======================
__global__ __launch_bounds__(256) void k_conv_gemm(const f16* __restrict__ xcl,
                                                   const f16* __restrict__ kern_hi,
                                                   const f16* __restrict__ kern_lo,
                                                   float* __restrict__ y) {
    __shared__ f16 As[128 * 32];
    __shared__ f16 Bh[128 * 32];
    __shared__ f16 Bl[128 * 32];
    int w = blockIdx.z;
    int m0 = blockIdx.y * 128, n0 = blockIdx.x * 128;
    const f16* xw = xcl + (size_t)w * 16 * 18 * 18 * 256;
    const f16* Bth = kern_hi + (size_t)w * 256 * 2304;
    const f16* Btl = kern_lo + (size_t)w * 256 * 2304;
    f32x4 acc[4][4] = {};
    int t = threadIdx.x;
    for (int k0 = 0; k0 < 2304; k0 += 32) {
        int k9 = k0 >> 8, ci0 = k0 & 255;
        int dy = k9 / 3, dx = k9 % 3;
#pragma unroll
        for (int c = 0; c < 2; c++) {
            int i = c * 256 + t;
            int row = i >> 2, part = i & 3;
            int m = m0 + row;
            int b = m >> 8, p = m & 255, py = p >> 4, px = p & 15;
            size_t go = ((size_t)(b * 18 + py + dy) * 18 + px + dx) * 256 + ci0 + (part << 3);
            uint4 v = *(const uint4*)(xw + go);
            *(uint4*)(As + row * 32 + ((part ^ (row & 3)) << 3)) = v;
        }
        stage_tile(Bth + (size_t)n0 * 2304 + k0, 2304, Bh);
        stage_tile(Btl + (size_t)n0 * 2304 + k0, 2304, Bl);
        __syncthreads();
        mfma_tile_f16(As, Bh, acc);
        mfma_tile_f16(As, Bl, acc);
        __syncthreads();
    }
    int lane = threadIdx.x & 63, wave = threadIdx.x >> 6;
    int wm = (wave >> 1) * 64, wn = (wave & 1) * 64;
    int lrow = lane & 15, quad = lane >> 4;
    float* yw = y + (size_t)w * 4096 * 256;
#pragma unroll
    for (int i = 0; i < 4; i++)
#pragma unroll
        for (int j = 0; j < 4; j++) {
            int col = n0 + wn + j * 16 + lrow;
#pragma unroll
            for (int rr = 0; rr < 4; rr++) {
                int row = m0 + wm + i * 16 + quad * 4 + rr;
                yw[(size_t)row * 256 + col] = acc[i][j][rr] * KSCALE_INV;
            }
        }
}

// ======================= layernorm + residual (+window reverse) =======================
__global__ __launch_bounds__(256) void k_ln_res(const float* __restrict__ y,
                                                const float* __restrict__ x,
                                                const float* __restrict__ g,
                                                const float* __restrict__ be,
                                                float* __restrict__ out) {
    int bx = blockIdx.x;          // b*64 + gy
    int b = bx >> 6, gy = bx & 63;
    int t = threadIdx.x;
    int j = t >> 2, sub = t & 3;  // j = gx, sub = channel quarter
    int w = (gy >> 4) * 4 + (j >> 4);
    int p = (gy & 15) * 16 + (j & 15);
    const float* yp = y + ((size_t)w * 4096 + b * 256 + p) * 256 + sub * 64;
    float vals[64];
    float sum = 0.f, sq = 0.f;
#pragma unroll
    for (int c = 0; c < 64; c++) {
        float v = yp[c];
        vals[c] = v;
        sum += v; sq += v * v;
    }
    sum += __shfl_xor(sum, 1); sq += __shfl_xor(sq, 1);
    sum += __shfl_xor(sum, 2); sq += __shfl_xor(sq, 2);
    float mean = sum * (1.f / 256.f);
    float var = sq * (1.f / 256.f) - mean * mean;
    float rstd = rsqrtf(var + 1e-5f);
    const float* xp = x + ((size_t)(b * 256 + sub * 64) * 64 + gy) * 64 + j;
    float* op = out + ((size_t)(b * 256 + sub * 64) * 64 + gy) * 64 + j;
#pragma unroll
    for (int c = 0; c < 64; c++) {
        int cc = sub * 64 + c;
        op[(size_t)c * 4096] = (vals[c] - mean) * rstd * g[cc] + be[cc] + xp[(size_t)c * 4096];
    }
}

// ======================= launch =======================
extern "C" void kernel_launch(void* const* d_in, const int* in_sizes, int n_in,
                              void* d_out, int out_size, void* d_ws, size_t ws_size,
                              hipStream_t stream) {
    const float* x      = (const float*)d_in[0];
    const float* conv_w = (const float*)d_in[1];
    const float* wqkv   = (const float*)d_in[2];
    const float* bqkv   = (const float*)d_in[3];
    const float* wout   = (const float*)d_in[4];
    const float* bout   = (const float*)d_in[5];
    const float* se_w1  = (const float*)d_in[6];
    const float* se_b1  = (const float*)d_in[7];
    const float* se_w2  = (const float*)d_in[8];
    const float* se_b2  = (const float*)d_in[9];
    const float* ln_g   = (const float*)d_in[10];
    const float* ln_b   = (const float*)d_in[11];
    float* out = (float*)d_out;

    // ---- workspace layout (lifetime-overlaid, 147,980,288 B) ----
    char* ws = (char*)d_ws;
    bf16*  kt      = (bf16*)(ws + 0);             // 18,874,368  kt -> o16 -> kern_hi
    f16*   o16     = (f16*)(ws + 0);
    f16*   kern_hi = (f16*)(ws + 0);
    f16*   kern_lo = (f16*)(ws + 18874368);       // 18,874,368
    bf16*  wqkv_t  = (bf16*)(ws + 37748736);      //    393,216
    f16*   wout_h  = (f16*)(ws + 38141952);       //    131,072
    f16*   wout_l  = (f16*)(ws + 38273024);       //    131,072
    f16*   xcl     = (f16*)(ws + 38404096);       // 42,467,328
    bf16*  qkv     = (bf16*)(ws + 80871424);      // 56,623,104  qkv -> kern_f -> y
    float* kern_f  = (float*)(ws + 80871424);     // 37,748,736
    float* y       = (float*)(ws + 80871424);     // 67,108,864

    k_prep_w<<<1024, 256, 0, stream>>>(wqkv, wout, wqkv_t, wout_h, wout_l);
    k_build_kt<<<4096, 256, 0, stream>>>(conv_w, kt);
    k_gemm_qkv<<<dim3(6, 288), 256, 0, stream>>>(kt, wqkv_t, bqkv, qkv, 768, 256);
    k_attn<<<2048, 256, 0, stream>>>(qkv, o16);
    k_gemm_split2<<<dim3(2, 288), 256, 0, stream>>>(o16, wout_h, wout_l, bout, kern_f, 256, 256);
    k_se_scale<<<4096, 256, 0, stream>>>(kern_f, se_w1, se_b1, se_w2, se_b2, kern_hi, kern_lo);
    k_zero<<<2048, 256, 0, stream>>>((uint4*)xcl, 42467328 / 16);
    k_fill_xcl<<<1024, 256, 0, stream>>>(x, xcl);
    k_conv_gemm<<<dim3(2, 32, 16), 256, 0, stream>>>(xcl, kern_hi, kern_lo, y);
    k_ln_res<<<1024, 256, 0, stream>>>(y, x, ln_g, ln_b, out);
}